// Round 4
// baseline (299.676 us; speedup 1.0000x reference)
//
#include <hip/hip_runtime.h>
#include <hip/hip_bf16.h>

// MultiHeadAttention fused pipeline, round 4: occupancy fix for attention.
// B=2 S=2048 D=1024 H=16 dk=64.
// ws layout (48 MB): Xb 8M | Wq/Wk/Wv/Wo bf16 2M each | Qb 8M | Kb 8M | Vt 8M | Ob 8M
// Changes vs R3:
//  - attn: 16 q-rows per wave (was 32) -> 4096 waves -> 4 waves/SIMD (was 2).
//    Same total MFMA/VALU work; pure latency-hiding. L1 dedups the 4 waves'
//    shared K/V tile reads; XCD mapping keeps 4 bh per XCD (2MB in 4MB L2).

typedef unsigned short u16;
typedef __attribute__((ext_vector_type(4))) unsigned short u16x4;
typedef __attribute__((ext_vector_type(8))) short short8;   // 8 x bf16 (4 VGPRs)
typedef __attribute__((ext_vector_type(4))) float f32x4;

__device__ __forceinline__ u16 f2bf(float f) {  // native RNE f32->bf16
  __bf16 b = (__bf16)f;
  return __builtin_bit_cast(unsigned short, b);
}

__device__ __forceinline__ f32x4 mfma_bf16(short8 a, short8 b, f32x4 c) {
  return __builtin_amdgcn_mfma_f32_16x16x32_bf16(a, b, c, 0, 0, 0);
}

#define GLL16(gp, lp) __builtin_amdgcn_global_load_lds( \
    (const __attribute__((address_space(1))) void*)(gp), \
    (__attribute__((address_space(3))) void*)(lp), 16, 0, 0)

#define QSCALE 0.18033688011112042f   /* 0.125 * log2(e) */

// ---------------------------------------------------------------- casts
__global__ __launch_bounds__(256) void cast_all(
    const float* __restrict__ x,
    const float* __restrict__ wq, const float* __restrict__ wk,
    const float* __restrict__ wv, const float* __restrict__ wo,
    u16* __restrict__ xb, u16* __restrict__ wqb, u16* __restrict__ wkb,
    u16* __restrict__ wvb, u16* __restrict__ wob)
{
  const int z = blockIdx.z;
  const float* s; u16* d; int n4;
  if (z == 0)      { s = x;  d = xb;  n4 = 1048576; }
  else if (z == 1) { s = wq; d = wqb; n4 = 262144; }
  else if (z == 2) { s = wk; d = wkb; n4 = 262144; }
  else if (z == 3) { s = wv; d = wvb; n4 = 262144; }
  else             { s = wo; d = wob; n4 = 262144; }
  int i = blockIdx.x * 256 + threadIdx.x;
  if (i >= n4) return;
  float4 v = ((const float4*)s)[i];
  u16x4 o; o[0] = f2bf(v.x); o[1] = f2bf(v.y); o[2] = f2bf(v.z); o[3] = f2bf(v.w);
  ((u16x4*)d)[i] = o;
}

// -------------------------------------------------- 128x128 GEMM core, C = A * B^T
__device__ __forceinline__ void gemm_core(const u16* __restrict__ A,
                                          const u16* __restrict__ B,
                                          u16* sA, u16* sB, f32x4 acc[4][4])
{
  const int tid = threadIdx.x;
  const int lane = tid & 63, wave = tid >> 6;
  const int wr = wave >> 1, wc = wave & 1;
  const int m0 = blockIdx.y * 128, n0 = blockIdx.x * 128;
  const u16* ga = A + (size_t)(m0 + (tid >> 2)) * 1024 + (tid & 3) * 8;
  const u16* gb = B + (size_t)(n0 + (tid >> 2)) * 1024 + (tid & 3) * 8;
  u16* la0 = sA + wave * 512;          u16* la1 = sA + 2048 + wave * 512;
  u16* lb0 = sB + wave * 512;          u16* lb1 = sB + 2048 + wave * 512;
  const int rl = lane & 15, kg = (lane >> 4) * 8;

  for (int k0 = 0; k0 < 1024; k0 += 32) {
    GLL16(ga + k0,             la0);
    GLL16(ga + 64 * 1024 + k0, la1);
    GLL16(gb + k0,             lb0);
    GLL16(gb + 64 * 1024 + k0, lb1);
    __syncthreads();
    short8 af[4], bf_[4];
#pragma unroll
    for (int m = 0; m < 4; ++m) af[m]  = *(const short8*)&sA[(wr * 64 + m * 16 + rl) * 32 + kg];
#pragma unroll
    for (int n = 0; n < 4; ++n) bf_[n] = *(const short8*)&sB[(wc * 64 + n * 16 + rl) * 32 + kg];
#pragma unroll
    for (int m = 0; m < 4; ++m)
#pragma unroll
      for (int n = 0; n < 4; ++n)
        acc[m][n] = mfma_bf16(af[m], bf_[n], acc[m][n]);
    __syncthreads();
  }
}

// QKV projections fused via blockIdx.z. z=0 -> Q (PRE-SCALED by QSCALE),
// z=1 -> K, z=2 -> V written TRANSPOSED: Vt[(b*1024+hd)][s].
__global__ __launch_bounds__(256) void gemm_qkv(
    const u16* __restrict__ X,
    const u16* __restrict__ Wqb, const u16* __restrict__ Wkb, const u16* __restrict__ Wvb,
    const float* __restrict__ bq, const float* __restrict__ bk, const float* __restrict__ bv,
    u16* __restrict__ Qo, u16* __restrict__ Ko, u16* __restrict__ Vt)
{
  __shared__ u16 sA[4096], sB[4096];
  const int z = blockIdx.z;
  const u16* W = (z == 0) ? Wqb : (z == 1) ? Wkb : Wvb;
  const float* bias = (z == 0) ? bq : (z == 1) ? bk : bv;

  f32x4 acc[4][4];
#pragma unroll
  for (int m = 0; m < 4; ++m)
#pragma unroll
    for (int n = 0; n < 4; ++n) acc[m][n] = (f32x4){0.f, 0.f, 0.f, 0.f};

  gemm_core(X, W, sA, sB, acc);

  const int lane = threadIdx.x & 63, wave = threadIdx.x >> 6;
  const int wr = wave >> 1, wc = wave & 1;
  const int m0 = blockIdx.y * 128, n0 = blockIdx.x * 128;
  const int rl = lane & 15, rg = (lane >> 4) * 4;

  if (z < 2) {
    u16* dst = (z == 0) ? Qo : Ko;
    const float cs = (z == 0) ? QSCALE : 1.0f;
#pragma unroll
    for (int n = 0; n < 4; ++n) {
      int col = n0 + wc * 64 + n * 16 + rl;
      float bb = bias[col];
#pragma unroll
      for (int m = 0; m < 4; ++m) {
        int row0 = m0 + wr * 64 + m * 16 + rg;
#pragma unroll
        for (int r = 0; r < 4; ++r)
          dst[(size_t)(row0 + r) * 1024 + col] = f2bf((acc[m][n][r] + bb) * cs);
      }
    }
  } else {
#pragma unroll
    for (int n = 0; n < 4; ++n) {
      int col = n0 + wc * 64 + n * 16 + rl;   // hd = h*64+d
      float bb = bias[col];
#pragma unroll
      for (int m = 0; m < 4; ++m) {
        int row0 = m0 + wr * 64 + m * 16 + rg;          // b*2048 + s
        int bidx = row0 >> 11, sl = row0 & 2047;
        u16x4 pk;
#pragma unroll
        for (int r = 0; r < 4; ++r) pk[r] = f2bf(acc[m][n][r] + bb);
        *(u16x4*)&Vt[((size_t)(bidx * 1024 + col)) * 2048 + sl] = pk;
      }
    }
  }
}

// Output projection: out(fp32) = Ob @ Wo^T + bo
__global__ __launch_bounds__(256) void gemm_out(
    const u16* __restrict__ Ob, const u16* __restrict__ Wob,
    const float* __restrict__ bo, float* __restrict__ Out)
{
  __shared__ u16 sA[4096], sB[4096];
  f32x4 acc[4][4];
#pragma unroll
  for (int m = 0; m < 4; ++m)
#pragma unroll
    for (int n = 0; n < 4; ++n) acc[m][n] = (f32x4){0.f, 0.f, 0.f, 0.f};

  gemm_core(Ob, Wob, sA, sB, acc);

  const int lane = threadIdx.x & 63, wave = threadIdx.x >> 6;
  const int wr = wave >> 1, wc = wave & 1;
  const int m0 = blockIdx.y * 128, n0 = blockIdx.x * 128;
  const int rl = lane & 15, rg = (lane >> 4) * 4;
#pragma unroll
  for (int n = 0; n < 4; ++n) {
    int col = n0 + wc * 64 + n * 16 + rl;
    float bb = bo[col];
#pragma unroll
    for (int m = 0; m < 4; ++m) {
      int row0 = m0 + wr * 64 + m * 16 + rg;
#pragma unroll
      for (int r = 0; r < 4; ++r)
        Out[(size_t)(row0 + r) * 1024 + col] = acc[m][n][r] + bb;
    }
  }
}

// ---------------------------------------------------------------- flash attention
// Swapped QK^T (mfma(K,Q)): lane owns one q-column, 8 keys per tile.
// K rows loaded PERMUTED so score C-regs are exactly the PV B-operand k-order.
// Q pre-scaled by 0.125*log2e -> scores already in exp2 domain.
// Wave = 16 q rows; block = 4 waves = 64 q rows; grid = 1024 blocks
// (= 4096 waves = 4 waves/SIMD). Block b -> XCD (b&7); XCD x owns bh in
// {4x..4x+3} -> 2MB K/V per XCD L2 (R3's residency preserved).
__global__ __launch_bounds__(256) void attn_fwd(
    const u16* __restrict__ Q, const u16* __restrict__ K,
    const u16* __restrict__ Vt, u16* __restrict__ O)
{
  const int tid = threadIdx.x, lane = tid & 63, wave = tid >> 6;
  const int rl = lane & 15, g = lane >> 4;

  const int bflat = blockIdx.x;
  const int xcd = bflat & 7, j = bflat >> 3;        // 1024 = 8 XCD * 128
  const int bh = xcd * 4 + (j >> 5);                // 4 bh per XCD
  const int qchunk = j & 31;                        // 32 chunks of 64 q rows
  const int b = bh >> 4, h = bh & 15;
  const int qbase = qchunk * 64 + wave * 16;

  const u16* Qp = Q + (size_t)(b * 2048 + qbase) * 1024 + h * 64;
  const u16* Kp = K + (size_t)(b * 2048) * 1024 + h * 64;
  const u16* Vp = Vt + (size_t)(bh * 64) * 2048;

  short8 qf[2];
#pragma unroll
  for (int hf = 0; hf < 2; ++hf)
    qf[hf] = *(const short8*)&Qp[(size_t)rl * 1024 + hf * 32 + g * 8];

  const int keyperm = 8 * (rl >> 2) + (rl & 3);

  f32x4 oacc[4];
  f32x4 lacc = (f32x4){0.f, 0.f, 0.f, 0.f};
#pragma unroll
  for (int dg = 0; dg < 4; ++dg) oacc[dg] = (f32x4){0.f, 0.f, 0.f, 0.f};
  float mrun = -INFINITY;

  const short8 ONES = {0x3F80, 0x3F80, 0x3F80, 0x3F80,
                       0x3F80, 0x3F80, 0x3F80, 0x3F80};  // bf16 1.0 x8

  auto loadtile = [&](int kt, short8 kf[2][2], short8 vf[4]) {
#pragma unroll
    for (int t = 0; t < 2; ++t) {
      const u16* kr = Kp + (size_t)(kt + keyperm + 4 * t) * 1024;
#pragma unroll
      for (int hf = 0; hf < 2; ++hf)
        kf[t][hf] = *(const short8*)&kr[hf * 32 + g * 8];
    }
#pragma unroll
    for (int dg = 0; dg < 4; ++dg)
      vf[dg] = *(const short8*)&Vp[(size_t)(dg * 16 + rl) * 2048 + kt + g * 8];
  };

  auto process = [&](const short8 kf[2][2], const short8 vf[4]) {
    f32x4 sc[2];
    __builtin_amdgcn_s_setprio(1);
#pragma unroll
    for (int t = 0; t < 2; ++t) {
      f32x4 a = (f32x4){0.f, 0.f, 0.f, 0.f};
      a = mfma_bf16(kf[t][0], qf[0], a);
      a = mfma_bf16(kf[t][1], qf[1], a);
      sc[t] = a;
    }
    __builtin_amdgcn_s_setprio(0);

    float p2[8];
#pragma unroll
    for (int t = 0; t < 2; ++t)
#pragma unroll
      for (int r = 0; r < 4; ++r) p2[t * 4 + r] = sc[t][r];
    // local max tree (max3-fusable)
    float a0 = fmaxf(fmaxf(p2[0], p2[1]), p2[2]);
    float a1 = fmaxf(fmaxf(p2[3], p2[4]), p2[5]);
    float a2 = fmaxf(p2[6], p2[7]);
    float tm = fmaxf(fmaxf(a0, a1), a2);
    // defer-max: only rescale when tile max grows past THR=8 (exp2 domain)
    if (!__all(tm <= mrun + 8.0f)) {
      tm = fmaxf(tm, __shfl_xor(tm, 16));
      tm = fmaxf(tm, __shfl_xor(tm, 32));
      float mnew = fmaxf(mrun, tm);
      float sfac = __builtin_amdgcn_exp2f(mrun - mnew);
      mrun = mnew;
#pragma unroll
      for (int dg = 0; dg < 4; ++dg)
#pragma unroll
        for (int r = 0; r < 4; ++r) oacc[dg][r] *= sfac;
      lacc[0] *= sfac;   // only reg 0 is ever read
    }
    short8 pb;
#pragma unroll
    for (int j2 = 0; j2 < 8; ++j2)
      pb[j2] = (short)f2bf(__builtin_amdgcn_exp2f(p2[j2] - mrun));

    __builtin_amdgcn_s_setprio(1);
    lacc = mfma_bf16(ONES, pb, lacc);   // row-sum on matrix pipe
#pragma unroll
    for (int dg = 0; dg < 4; ++dg)
      oacc[dg] = mfma_bf16(vf[dg], pb, oacc[dg]);
    __builtin_amdgcn_s_setprio(0);
  };

  // register ping-pong double buffer over 64 tiles of 32 keys
  short8 kfA[2][2], vfA[4], kfB[2][2], vfB[4];
  loadtile(0, kfA, vfA);
  for (int kt = 0; kt < 2048; kt += 64) {
    loadtile((kt + 32) & 2047, kfB, vfB);   // wrap-masked: tail prefetch is unused
    process(kfA, vfA);
    loadtile((kt + 64) & 2047, kfA, vfA);
    process(kfB, vfB);
  }

  float inv = 1.0f / lacc[0];
  int qrow = qbase + rl;
  u16* op = O + (size_t)(b * 2048 + qrow) * 1024 + h * 64;
#pragma unroll
  for (int dg = 0; dg < 4; ++dg) {
    u16x4 pk;
#pragma unroll
    for (int r = 0; r < 4; ++r) pk[r] = f2bf(oacc[dg][r] * inv);
    *(u16x4*)&op[dg * 16 + g * 4] = pk;
  }
}

// ---------------------------------------------------------------- launch
extern "C" void kernel_launch(void* const* d_in, const int* in_sizes, int n_in,
                              void* d_out, int out_size, void* d_ws, size_t ws_size,
                              hipStream_t stream) {
  const float* x  = (const float*)d_in[0];
  const float* Wq = (const float*)d_in[1];
  const float* bq = (const float*)d_in[2];
  const float* Wk = (const float*)d_in[3];
  const float* bk = (const float*)d_in[4];
  const float* Wv = (const float*)d_in[5];
  const float* bv = (const float*)d_in[6];
  const float* Wo = (const float*)d_in[7];
  const float* bo = (const float*)d_in[8];

  char* ws = (char*)d_ws;
  const size_t MB = 1024 * 1024;
  u16* Xb  = (u16*)(ws + 0 * MB);
  u16* Wqb = (u16*)(ws + 8 * MB);
  u16* Wkb = (u16*)(ws + 10 * MB);
  u16* Wvb = (u16*)(ws + 12 * MB);
  u16* Wob = (u16*)(ws + 14 * MB);
  u16* Qb  = (u16*)(ws + 16 * MB);
  u16* Kb  = (u16*)(ws + 24 * MB);
  u16* Vtb = (u16*)(ws + 32 * MB);
  u16* Ob  = (u16*)(ws + 40 * MB);

  cast_all<<<dim3(4096, 1, 5), 256, 0, stream>>>(x, Wq, Wk, Wv, Wo,
                                                 Xb, Wqb, Wkb, Wvb, Wob);
  gemm_qkv<<<dim3(8, 32, 3), 256, 0, stream>>>(Xb, Wqb, Wkb, Wvb,
                                               bq, bk, bv, Qb, Kb, Vtb);
  attn_fwd<<<dim3(1024), 256, 0, stream>>>(Qb, Kb, Vtb, Ob);
  gemm_out<<<dim3(8, 32), 256, 0, stream>>>(Ob, Wob, bo, (float*)d_out);
}

// Round 5
// 120.387 us; speedup vs baseline: 2.4893x; 2.4893x over previous
//
#include <hip/hip_runtime.h>
#include <hip/hip_bf16.h>

// MultiHeadAttention fused pipeline, round 5: LDS-staged K/V attention.
// B=2 S=2048 D=1024 H=16 dk=64.
// ws layout (48 MB): Xb 8M | Wq/Wk/Wv/Wo bf16 2M each | Qb 8M | Kb 8M | Vt 8M | Ob 8M
// Changes vs R4:
//  - attn: back to 32 q-rows/wave, 512 blocks (R3 geometry / XCD map)
//  - K/V tiles (64 keys) staged into double-buffered LDS via global_load_lds
//    ONCE per block, shared by 4 waves: 4x fewer global load instrs, and the
//    saturated scattered-L1 path is replaced by swizzled conflict-free ds_read.
//    (R1-R4 evidence: dur tracks load-instr count at ~75cyc/instr per CU.)

typedef unsigned short u16;
typedef __attribute__((ext_vector_type(4))) unsigned short u16x4;
typedef __attribute__((ext_vector_type(8))) short short8;   // 8 x bf16 (4 VGPRs)
typedef __attribute__((ext_vector_type(4))) float f32x4;

__device__ __forceinline__ u16 f2bf(float f) {  // native RNE f32->bf16
  __bf16 b = (__bf16)f;
  return __builtin_bit_cast(unsigned short, b);
}

__device__ __forceinline__ f32x4 mfma_bf16(short8 a, short8 b, f32x4 c) {
  return __builtin_amdgcn_mfma_f32_16x16x32_bf16(a, b, c, 0, 0, 0);
}

#define GLL16(gp, lp) __builtin_amdgcn_global_load_lds( \
    (const __attribute__((address_space(1))) void*)(gp), \
    (__attribute__((address_space(3))) void*)(lp), 16, 0, 0)

#define QSCALE 0.18033688011112042f   /* 0.125 * log2(e) */

// ---------------------------------------------------------------- casts
__global__ __launch_bounds__(256) void cast_all(
    const float* __restrict__ x,
    const float* __restrict__ wq, const float* __restrict__ wk,
    const float* __restrict__ wv, const float* __restrict__ wo,
    u16* __restrict__ xb, u16* __restrict__ wqb, u16* __restrict__ wkb,
    u16* __restrict__ wvb, u16* __restrict__ wob)
{
  const int z = blockIdx.z;
  const float* s; u16* d; int n4;
  if (z == 0)      { s = x;  d = xb;  n4 = 1048576; }
  else if (z == 1) { s = wq; d = wqb; n4 = 262144; }
  else if (z == 2) { s = wk; d = wkb; n4 = 262144; }
  else if (z == 3) { s = wv; d = wvb; n4 = 262144; }
  else             { s = wo; d = wob; n4 = 262144; }
  int i = blockIdx.x * 256 + threadIdx.x;
  if (i >= n4) return;
  float4 v = ((const float4*)s)[i];
  u16x4 o; o[0] = f2bf(v.x); o[1] = f2bf(v.y); o[2] = f2bf(v.z); o[3] = f2bf(v.w);
  ((u16x4*)d)[i] = o;
}

// -------------------------------------------------- 128x128 GEMM core, C = A * B^T
__device__ __forceinline__ void gemm_core(const u16* __restrict__ A,
                                          const u16* __restrict__ B,
                                          u16* sA, u16* sB, f32x4 acc[4][4])
{
  const int tid = threadIdx.x;
  const int lane = tid & 63, wave = tid >> 6;
  const int wr = wave >> 1, wc = wave & 1;
  const int m0 = blockIdx.y * 128, n0 = blockIdx.x * 128;
  const u16* ga = A + (size_t)(m0 + (tid >> 2)) * 1024 + (tid & 3) * 8;
  const u16* gb = B + (size_t)(n0 + (tid >> 2)) * 1024 + (tid & 3) * 8;
  u16* la0 = sA + wave * 512;          u16* la1 = sA + 2048 + wave * 512;
  u16* lb0 = sB + wave * 512;          u16* lb1 = sB + 2048 + wave * 512;
  const int rl = lane & 15, kg = (lane >> 4) * 8;

  for (int k0 = 0; k0 < 1024; k0 += 32) {
    GLL16(ga + k0,             la0);
    GLL16(ga + 64 * 1024 + k0, la1);
    GLL16(gb + k0,             lb0);
    GLL16(gb + 64 * 1024 + k0, lb1);
    __syncthreads();
    short8 af[4], bf_[4];
#pragma unroll
    for (int m = 0; m < 4; ++m) af[m]  = *(const short8*)&sA[(wr * 64 + m * 16 + rl) * 32 + kg];
#pragma unroll
    for (int n = 0; n < 4; ++n) bf_[n] = *(const short8*)&sB[(wc * 64 + n * 16 + rl) * 32 + kg];
#pragma unroll
    for (int m = 0; m < 4; ++m)
#pragma unroll
      for (int n = 0; n < 4; ++n)
        acc[m][n] = mfma_bf16(af[m], bf_[n], acc[m][n]);
    __syncthreads();
  }
}

// QKV projections fused via blockIdx.z. z=0 -> Q (PRE-SCALED by QSCALE),
// z=1 -> K, z=2 -> V written TRANSPOSED: Vt[(b*1024+hd)][s].
__global__ __launch_bounds__(256) void gemm_qkv(
    const u16* __restrict__ X,
    const u16* __restrict__ Wqb, const u16* __restrict__ Wkb, const u16* __restrict__ Wvb,
    const float* __restrict__ bq, const float* __restrict__ bk, const float* __restrict__ bv,
    u16* __restrict__ Qo, u16* __restrict__ Ko, u16* __restrict__ Vt)
{
  __shared__ u16 sA[4096], sB[4096];
  const int z = blockIdx.z;
  const u16* W = (z == 0) ? Wqb : (z == 1) ? Wkb : Wvb;
  const float* bias = (z == 0) ? bq : (z == 1) ? bk : bv;

  f32x4 acc[4][4];
#pragma unroll
  for (int m = 0; m < 4; ++m)
#pragma unroll
    for (int n = 0; n < 4; ++n) acc[m][n] = (f32x4){0.f, 0.f, 0.f, 0.f};

  gemm_core(X, W, sA, sB, acc);

  const int lane = threadIdx.x & 63, wave = threadIdx.x >> 6;
  const int wr = wave >> 1, wc = wave & 1;
  const int m0 = blockIdx.y * 128, n0 = blockIdx.x * 128;
  const int rl = lane & 15, rg = (lane >> 4) * 4;

  if (z < 2) {
    u16* dst = (z == 0) ? Qo : Ko;
    const float cs = (z == 0) ? QSCALE : 1.0f;
#pragma unroll
    for (int n = 0; n < 4; ++n) {
      int col = n0 + wc * 64 + n * 16 + rl;
      float bb = bias[col];
#pragma unroll
      for (int m = 0; m < 4; ++m) {
        int row0 = m0 + wr * 64 + m * 16 + rg;
#pragma unroll
        for (int r = 0; r < 4; ++r)
          dst[(size_t)(row0 + r) * 1024 + col] = f2bf((acc[m][n][r] + bb) * cs);
      }
    }
  } else {
#pragma unroll
    for (int n = 0; n < 4; ++n) {
      int col = n0 + wc * 64 + n * 16 + rl;   // hd = h*64+d
      float bb = bias[col];
#pragma unroll
      for (int m = 0; m < 4; ++m) {
        int row0 = m0 + wr * 64 + m * 16 + rg;          // b*2048 + s
        int bidx = row0 >> 11, sl = row0 & 2047;
        u16x4 pk;
#pragma unroll
        for (int r = 0; r < 4; ++r) pk[r] = f2bf(acc[m][n][r] + bb);
        *(u16x4*)&Vt[((size_t)(bidx * 1024 + col)) * 2048 + sl] = pk;
      }
    }
  }
}

// Output projection: out(fp32) = Ob @ Wo^T + bo
__global__ __launch_bounds__(256) void gemm_out(
    const u16* __restrict__ Ob, const u16* __restrict__ Wob,
    const float* __restrict__ bo, float* __restrict__ Out)
{
  __shared__ u16 sA[4096], sB[4096];
  f32x4 acc[4][4];
#pragma unroll
  for (int m = 0; m < 4; ++m)
#pragma unroll
    for (int n = 0; n < 4; ++n) acc[m][n] = (f32x4){0.f, 0.f, 0.f, 0.f};

  gemm_core(Ob, Wob, sA, sB, acc);

  const int lane = threadIdx.x & 63, wave = threadIdx.x >> 6;
  const int wr = wave >> 1, wc = wave & 1;
  const int m0 = blockIdx.y * 128, n0 = blockIdx.x * 128;
  const int rl = lane & 15, rg = (lane >> 4) * 4;
#pragma unroll
  for (int n = 0; n < 4; ++n) {
    int col = n0 + wc * 64 + n * 16 + rl;
    float bb = bo[col];
#pragma unroll
    for (int m = 0; m < 4; ++m) {
      int row0 = m0 + wr * 64 + m * 16 + rg;
#pragma unroll
      for (int r = 0; r < 4; ++r)
        Out[(size_t)(row0 + r) * 1024 + col] = acc[m][n][r] + bb;
    }
  }
}

// ---------------------------------------------------------------- flash attention
// Swapped QK^T (mfma(K,Q)): lane owns one q-column, 8 keys per 32-key subtile.
// K rows read PERMUTED from LDS so score C-regs match PV B-operand k-order.
// Q pre-scaled by 0.125*log2e -> scores in exp2 domain.
// K/V staged per 64-key tile into double-buffered, XOR-swizzled LDS via
// global_load_lds (linear dest + inverse-swizzled global source; rule 21).
// Wave = 32 q rows; block = 4 waves = 128 q rows; grid = 512 (XCD-resident K/V).
__global__ __launch_bounds__(256) void attn_fwd(
    const u16* __restrict__ Q, const u16* __restrict__ K,
    const u16* __restrict__ Vt, u16* __restrict__ O)
{
  __shared__ u16 sK[2][64][64];   // [buf][key row][d elems], elem-swizzled
  __shared__ u16 sV[2][64][64];   // [buf][d row][key elems], elem-swizzled

  const int tid = threadIdx.x, lane = tid & 63, wave = tid >> 6;
  const int rl = lane & 15, g = lane >> 4;

  const int bflat = blockIdx.x;
  const int xcd = bflat & 7, j = bflat >> 3;        // 512 = 8 XCD * 64
  const int bh = xcd * 4 + (j >> 4);                // 4 bh per XCD (2MB in L2)
  const int qchunk = j & 15;
  const int b = bh >> 4, h = bh & 15;
  const int qbase = qchunk * 128 + wave * 32;

  const u16* Qp = Q + (size_t)(b * 2048 + qbase) * 1024 + h * 64;
  const u16* Kp = K + (size_t)(b * 2048) * 1024 + h * 64;
  const u16* Vp = Vt + (size_t)(bh * 64) * 2048;

  short8 qf[2][2];
#pragma unroll
  for (int qg = 0; qg < 2; ++qg)
#pragma unroll
    for (int hf = 0; hf < 2; ++hf)
      qf[qg][hf] = *(const short8*)&Qp[(size_t)(qg * 16 + rl) * 1024 + hf * 32 + g * 8];

  const int keyperm = 8 * (rl >> 2) + (rl & 3);
  // K read swizzle (elements): swzK(r) = (r&3)|(((r>>3)&1)<<2); r bits from rl only
  const int swzK8 = (((rl & 3) | (((rl >> 2) & 1) << 2))) * 8;
  // V read swizzle: swzV(r) = r&7 with r = dg*16+rl -> rl&7
  const int swzV8 = (rl & 7) * 8;

  // staging address precompute (thread-constant)
  const int srow = lane >> 3;                       // row within 8-row chunk
  const int feK = (((lane & 7) * 8) ^ ((srow & 3) * 8));  // ^ (c*32) per chunk
  const int feV = (((lane & 7) ^ srow) * 8);

  f32x4 oacc[2][4];
  f32x4 lacc[2];
#pragma unroll
  for (int qg = 0; qg < 2; ++qg) {
    lacc[qg] = (f32x4){0.f, 0.f, 0.f, 0.f};
#pragma unroll
    for (int dg = 0; dg < 4; ++dg) oacc[qg][dg] = (f32x4){0.f, 0.f, 0.f, 0.f};
  }
  float mrun[2] = {-INFINITY, -INFINITY};

  const short8 ONES = {0x3F80, 0x3F80, 0x3F80, 0x3F80,
                       0x3F80, 0x3F80, 0x3F80, 0x3F80};  // bf16 1.0 x8

  // stage one 64-key tile (K 8KB + V 8KB) into buffer nb
  auto stage = [&](int nb, int kt) {
#pragma unroll
    for (int c = 0; c < 2; ++c) {
      const int chunk = wave * 2 + c;               // 0..7, wave-uniform
      const int grow = chunk * 8 + srow;            // 0..63
      GLL16(Kp + (size_t)(kt + grow) * 1024 + (feK ^ (c * 32)),
            &sK[nb][chunk * 8][0]);
      GLL16(Vp + (size_t)grow * 2048 + kt + feV,
            &sV[nb][chunk * 8][0]);
    }
  };

  // process one 32-key subtile from buffer nb
  auto proc_sub = [&](int nb, int sub) {
    short8 kf[2][2];
#pragma unroll
    for (int t = 0; t < 2; ++t) {
      const int r = sub * 32 + keyperm + 4 * t;
#pragma unroll
      for (int hf = 0; hf < 2; ++hf)
        kf[t][hf] = *(const short8*)&sK[nb][r][(hf * 32 + g * 8) ^ swzK8];
    }
    short8 vf[4];
#pragma unroll
    for (int dg = 0; dg < 4; ++dg)
      vf[dg] = *(const short8*)&sV[nb][dg * 16 + rl][(sub * 32 + g * 8) ^ swzV8];

    f32x4 sc[2][2];
    __builtin_amdgcn_s_setprio(1);
#pragma unroll
    for (int qg = 0; qg < 2; ++qg)
#pragma unroll
      for (int t = 0; t < 2; ++t) {
        f32x4 a = (f32x4){0.f, 0.f, 0.f, 0.f};
        a = mfma_bf16(kf[t][0], qf[qg][0], a);
        a = mfma_bf16(kf[t][1], qf[qg][1], a);
        sc[qg][t] = a;
      }
    __builtin_amdgcn_s_setprio(0);

    short8 pb[2];
#pragma unroll
    for (int qg = 0; qg < 2; ++qg) {
      float p2[8];
#pragma unroll
      for (int t = 0; t < 2; ++t)
#pragma unroll
        for (int r = 0; r < 4; ++r) p2[t * 4 + r] = sc[qg][t][r];
      float a0 = fmaxf(fmaxf(p2[0], p2[1]), p2[2]);
      float a1 = fmaxf(fmaxf(p2[3], p2[4]), p2[5]);
      float a2 = fmaxf(p2[6], p2[7]);
      float tm = fmaxf(fmaxf(a0, a1), a2);
      // defer-max: rescale only when tile max grows past THR=8 (exp2 domain)
      if (!__all(tm <= mrun[qg] + 8.0f)) {
        tm = fmaxf(tm, __shfl_xor(tm, 16));
        tm = fmaxf(tm, __shfl_xor(tm, 32));
        float mnew = fmaxf(mrun[qg], tm);
        float sfac = __builtin_amdgcn_exp2f(mrun[qg] - mnew);
        mrun[qg] = mnew;
#pragma unroll
        for (int dg = 0; dg < 4; ++dg)
#pragma unroll
          for (int r = 0; r < 4; ++r) oacc[qg][dg][r] *= sfac;
        lacc[qg][0] *= sfac;   // only reg 0 is ever read
      }
      short8 pk;
#pragma unroll
      for (int j2 = 0; j2 < 8; ++j2)
        pk[j2] = (short)f2bf(__builtin_amdgcn_exp2f(p2[j2] - mrun[qg]));
      pb[qg] = pk;
      lacc[qg] = mfma_bf16(ONES, pb[qg], lacc[qg]);   // row-sum on matrix pipe
    }
    __builtin_amdgcn_s_setprio(1);
#pragma unroll
    for (int dg = 0; dg < 4; ++dg)
#pragma unroll
      for (int qg = 0; qg < 2; ++qg)
        oacc[qg][dg] = mfma_bf16(vf[dg], pb[qg], oacc[qg][dg]);
    __builtin_amdgcn_s_setprio(0);
  };

  // double-buffered main loop: 32 tiles of 64 keys, unrolled x2 (static nb)
  stage(0, 0);
  __syncthreads();
  for (int kt = 0; kt < 2048; kt += 128) {
    stage(1, kt + 64);
    proc_sub(0, 0);
    proc_sub(0, 1);
    __syncthreads();                     // buf1 staged; buf0 fully read
    if (kt + 128 < 2048) stage(0, kt + 128);
    proc_sub(1, 0);
    proc_sub(1, 1);
    __syncthreads();
  }

#pragma unroll
  for (int qg = 0; qg < 2; ++qg) {
    float inv = 1.0f / lacc[qg][0];
    int qrow = qbase + qg * 16 + rl;
    u16* op = O + (size_t)(b * 2048 + qrow) * 1024 + h * 64;
#pragma unroll
    for (int dg = 0; dg < 4; ++dg) {
      u16x4 pk;
#pragma unroll
      for (int r = 0; r < 4; ++r) pk[r] = f2bf(oacc[qg][dg][r] * inv);
      *(u16x4*)&op[dg * 16 + g * 4] = pk;
    }
  }
}

// ---------------------------------------------------------------- launch
extern "C" void kernel_launch(void* const* d_in, const int* in_sizes, int n_in,
                              void* d_out, int out_size, void* d_ws, size_t ws_size,
                              hipStream_t stream) {
  const float* x  = (const float*)d_in[0];
  const float* Wq = (const float*)d_in[1];
  const float* bq = (const float*)d_in[2];
  const float* Wk = (const float*)d_in[3];
  const float* bk = (const float*)d_in[4];
  const float* Wv = (const float*)d_in[5];
  const float* bv = (const float*)d_in[6];
  const float* Wo = (const float*)d_in[7];
  const float* bo = (const float*)d_in[8];

  char* ws = (char*)d_ws;
  const size_t MB = 1024 * 1024;
  u16* Xb  = (u16*)(ws + 0 * MB);
  u16* Wqb = (u16*)(ws + 8 * MB);
  u16* Wkb = (u16*)(ws + 10 * MB);
  u16* Wvb = (u16*)(ws + 12 * MB);
  u16* Wob = (u16*)(ws + 14 * MB);
  u16* Qb  = (u16*)(ws + 16 * MB);
  u16* Kb  = (u16*)(ws + 24 * MB);
  u16* Vtb = (u16*)(ws + 32 * MB);
  u16* Ob  = (u16*)(ws + 40 * MB);

  cast_all<<<dim3(4096, 1, 5), 256, 0, stream>>>(x, Wq, Wk, Wv, Wo,
                                                 Xb, Wqb, Wkb, Wvb, Wob);
  gemm_qkv<<<dim3(8, 32, 3), 256, 0, stream>>>(Xb, Wqb, Wkb, Wvb,
                                               bq, bk, bv, Qb, Kb, Vtb);
  attn_fwd<<<dim3(512), 256, 0, stream>>>(Qb, Kb, Vtb, Ob);
  gemm_out<<<dim3(8, 32), 256, 0, stream>>>(Ob, Wob, bo, (float*)d_out);
}

// Round 6
// 117.010 us; speedup vs baseline: 2.5611x; 1.0289x over previous
//
#include <hip/hip_runtime.h>
#include <hip/hip_bf16.h>

// MultiHeadAttention fused pipeline, round 6: 8-wave attention blocks (TLP x2).
// B=2 S=2048 D=1024 H=16 dk=64.
// ws layout (48 MB): Xb 8M | Wq/Wk/Wv/Wo bf16 2M each | Qb 8M | Kb 8M | Vt 8M | Ob 8M
// Changes vs R5:
//  - attn: 512-thread blocks, 8 waves x 16 q-rows (was 4 x 32). Same grid (512),
//    same per-block LDS staging traffic, same total MFMA/VALU work -> pure TLP:
//    2 -> 4 waves/SIMD to cover the serial QK^T->softmax->PV chain.

typedef unsigned short u16;
typedef __attribute__((ext_vector_type(4))) unsigned short u16x4;
typedef __attribute__((ext_vector_type(8))) short short8;   // 8 x bf16 (4 VGPRs)
typedef __attribute__((ext_vector_type(4))) float f32x4;

__device__ __forceinline__ u16 f2bf(float f) {  // native RNE f32->bf16
  __bf16 b = (__bf16)f;
  return __builtin_bit_cast(unsigned short, b);
}

__device__ __forceinline__ f32x4 mfma_bf16(short8 a, short8 b, f32x4 c) {
  return __builtin_amdgcn_mfma_f32_16x16x32_bf16(a, b, c, 0, 0, 0);
}

#define GLL16(gp, lp) __builtin_amdgcn_global_load_lds( \
    (const __attribute__((address_space(1))) void*)(gp), \
    (__attribute__((address_space(3))) void*)(lp), 16, 0, 0)

#define QSCALE 0.18033688011112042f   /* 0.125 * log2(e) */

// ---------------------------------------------------------------- casts
__global__ __launch_bounds__(256) void cast_all(
    const float* __restrict__ x,
    const float* __restrict__ wq, const float* __restrict__ wk,
    const float* __restrict__ wv, const float* __restrict__ wo,
    u16* __restrict__ xb, u16* __restrict__ wqb, u16* __restrict__ wkb,
    u16* __restrict__ wvb, u16* __restrict__ wob)
{
  const int z = blockIdx.z;
  const float* s; u16* d; int n4;
  if (z == 0)      { s = x;  d = xb;  n4 = 1048576; }
  else if (z == 1) { s = wq; d = wqb; n4 = 262144; }
  else if (z == 2) { s = wk; d = wkb; n4 = 262144; }
  else if (z == 3) { s = wv; d = wvb; n4 = 262144; }
  else             { s = wo; d = wob; n4 = 262144; }
  int i = blockIdx.x * 256 + threadIdx.x;
  if (i >= n4) return;
  float4 v = ((const float4*)s)[i];
  u16x4 o; o[0] = f2bf(v.x); o[1] = f2bf(v.y); o[2] = f2bf(v.z); o[3] = f2bf(v.w);
  ((u16x4*)d)[i] = o;
}

// -------------------------------------------------- 128x128 GEMM core, C = A * B^T
__device__ __forceinline__ void gemm_core(const u16* __restrict__ A,
                                          const u16* __restrict__ B,
                                          u16* sA, u16* sB, f32x4 acc[4][4])
{
  const int tid = threadIdx.x;
  const int lane = tid & 63, wave = tid >> 6;
  const int wr = wave >> 1, wc = wave & 1;
  const int m0 = blockIdx.y * 128, n0 = blockIdx.x * 128;
  const u16* ga = A + (size_t)(m0 + (tid >> 2)) * 1024 + (tid & 3) * 8;
  const u16* gb = B + (size_t)(n0 + (tid >> 2)) * 1024 + (tid & 3) * 8;
  u16* la0 = sA + wave * 512;          u16* la1 = sA + 2048 + wave * 512;
  u16* lb0 = sB + wave * 512;          u16* lb1 = sB + 2048 + wave * 512;
  const int rl = lane & 15, kg = (lane >> 4) * 8;

  for (int k0 = 0; k0 < 1024; k0 += 32) {
    GLL16(ga + k0,             la0);
    GLL16(ga + 64 * 1024 + k0, la1);
    GLL16(gb + k0,             lb0);
    GLL16(gb + 64 * 1024 + k0, lb1);
    __syncthreads();
    short8 af[4], bf_[4];
#pragma unroll
    for (int m = 0; m < 4; ++m) af[m]  = *(const short8*)&sA[(wr * 64 + m * 16 + rl) * 32 + kg];
#pragma unroll
    for (int n = 0; n < 4; ++n) bf_[n] = *(const short8*)&sB[(wc * 64 + n * 16 + rl) * 32 + kg];
#pragma unroll
    for (int m = 0; m < 4; ++m)
#pragma unroll
      for (int n = 0; n < 4; ++n)
        acc[m][n] = mfma_bf16(af[m], bf_[n], acc[m][n]);
    __syncthreads();
  }
}

// QKV projections fused via blockIdx.z. z=0 -> Q (PRE-SCALED by QSCALE),
// z=1 -> K, z=2 -> V written TRANSPOSED: Vt[(b*1024+hd)][s].
__global__ __launch_bounds__(256) void gemm_qkv(
    const u16* __restrict__ X,
    const u16* __restrict__ Wqb, const u16* __restrict__ Wkb, const u16* __restrict__ Wvb,
    const float* __restrict__ bq, const float* __restrict__ bk, const float* __restrict__ bv,
    u16* __restrict__ Qo, u16* __restrict__ Ko, u16* __restrict__ Vt)
{
  __shared__ u16 sA[4096], sB[4096];
  const int z = blockIdx.z;
  const u16* W = (z == 0) ? Wqb : (z == 1) ? Wkb : Wvb;
  const float* bias = (z == 0) ? bq : (z == 1) ? bk : bv;

  f32x4 acc[4][4];
#pragma unroll
  for (int m = 0; m < 4; ++m)
#pragma unroll
    for (int n = 0; n < 4; ++n) acc[m][n] = (f32x4){0.f, 0.f, 0.f, 0.f};

  gemm_core(X, W, sA, sB, acc);

  const int lane = threadIdx.x & 63, wave = threadIdx.x >> 6;
  const int wr = wave >> 1, wc = wave & 1;
  const int m0 = blockIdx.y * 128, n0 = blockIdx.x * 128;
  const int rl = lane & 15, rg = (lane >> 4) * 4;

  if (z < 2) {
    u16* dst = (z == 0) ? Qo : Ko;
    const float cs = (z == 0) ? QSCALE : 1.0f;
#pragma unroll
    for (int n = 0; n < 4; ++n) {
      int col = n0 + wc * 64 + n * 16 + rl;
      float bb = bias[col];
#pragma unroll
      for (int m = 0; m < 4; ++m) {
        int row0 = m0 + wr * 64 + m * 16 + rg;
#pragma unroll
        for (int r = 0; r < 4; ++r)
          dst[(size_t)(row0 + r) * 1024 + col] = f2bf((acc[m][n][r] + bb) * cs);
      }
    }
  } else {
#pragma unroll
    for (int n = 0; n < 4; ++n) {
      int col = n0 + wc * 64 + n * 16 + rl;   // hd = h*64+d
      float bb = bias[col];
#pragma unroll
      for (int m = 0; m < 4; ++m) {
        int row0 = m0 + wr * 64 + m * 16 + rg;          // b*2048 + s
        int bidx = row0 >> 11, sl = row0 & 2047;
        u16x4 pk;
#pragma unroll
        for (int r = 0; r < 4; ++r) pk[r] = f2bf(acc[m][n][r] + bb);
        *(u16x4*)&Vt[((size_t)(bidx * 1024 + col)) * 2048 + sl] = pk;
      }
    }
  }
}

// Output projection: out(fp32) = Ob @ Wo^T + bo
__global__ __launch_bounds__(256) void gemm_out(
    const u16* __restrict__ Ob, const u16* __restrict__ Wob,
    const float* __restrict__ bo, float* __restrict__ Out)
{
  __shared__ u16 sA[4096], sB[4096];
  f32x4 acc[4][4];
#pragma unroll
  for (int m = 0; m < 4; ++m)
#pragma unroll
    for (int n = 0; n < 4; ++n) acc[m][n] = (f32x4){0.f, 0.f, 0.f, 0.f};

  gemm_core(Ob, Wob, sA, sB, acc);

  const int lane = threadIdx.x & 63, wave = threadIdx.x >> 6;
  const int wr = wave >> 1, wc = wave & 1;
  const int m0 = blockIdx.y * 128, n0 = blockIdx.x * 128;
  const int rl = lane & 15, rg = (lane >> 4) * 4;
#pragma unroll
  for (int n = 0; n < 4; ++n) {
    int col = n0 + wc * 64 + n * 16 + rl;
    float bb = bo[col];
#pragma unroll
    for (int m = 0; m < 4; ++m) {
      int row0 = m0 + wr * 64 + m * 16 + rg;
#pragma unroll
      for (int r = 0; r < 4; ++r)
        Out[(size_t)(row0 + r) * 1024 + col] = acc[m][n][r] + bb;
    }
  }
}

// ---------------------------------------------------------------- flash attention
// Swapped QK^T (mfma(K,Q)): lane owns one q-column, 8 keys per 32-key subtile.
// K rows read PERMUTED from LDS so score C-regs match PV B-operand k-order.
// Q pre-scaled by 0.125*log2e -> scores in exp2 domain.
// K/V staged per 64-key tile into double-buffered, XOR-swizzled LDS via
// global_load_lds (linear dest + inverse-swizzled global source; rule 21).
// Wave = 16 q rows; block = 8 waves (512 thr) = 128 q rows; grid = 512
// -> 4096 waves = 4 waves/SIMD. XCD-resident K/V (4 bh per XCD) preserved.
__global__ __launch_bounds__(512) void attn_fwd(
    const u16* __restrict__ Q, const u16* __restrict__ K,
    const u16* __restrict__ Vt, u16* __restrict__ O)
{
  __shared__ u16 sK[2][64][64];   // [buf][key row][d elems], elem-swizzled
  __shared__ u16 sV[2][64][64];   // [buf][d row][key elems], elem-swizzled

  const int tid = threadIdx.x, lane = tid & 63, wave = tid >> 6;  // wave 0..7
  const int rl = lane & 15, g = lane >> 4;

  const int bflat = blockIdx.x;
  const int xcd = bflat & 7, j = bflat >> 3;        // 512 = 8 XCD * 64
  const int bh = xcd * 4 + (j >> 4);                // 4 bh per XCD (2MB in L2)
  const int qchunk = j & 15;
  const int b = bh >> 4, h = bh & 15;
  const int qbase = qchunk * 128 + wave * 16;

  const u16* Qp = Q + (size_t)(b * 2048 + qbase) * 1024 + h * 64;
  const u16* Kp = K + (size_t)(b * 2048) * 1024 + h * 64;
  const u16* Vp = Vt + (size_t)(bh * 64) * 2048;

  short8 qf[2];
#pragma unroll
  for (int hf = 0; hf < 2; ++hf)
    qf[hf] = *(const short8*)&Qp[(size_t)rl * 1024 + hf * 32 + g * 8];

  const int keyperm = 8 * (rl >> 2) + (rl & 3);
  // K read swizzle (elements): swzK(r) = (r&3)|(((r>>3)&1)<<2); r bits from rl only
  const int swzK8 = (((rl & 3) | (((rl >> 2) & 1) << 2))) * 8;
  // V read swizzle: swzV(r) = r&7 with r = dg*16+rl -> rl&7
  const int swzV8 = (rl & 7) * 8;

  // staging address precompute (thread-constant); chunk = wave (0..7)
  const int srow = lane >> 3;                       // row within 8-row chunk
  const int feK = (((lane & 7) ^ (srow & 3)) * 8) ^ ((wave & 1) * 32);
  const int feV = (((lane & 7) ^ srow) * 8);

  f32x4 oacc[4];
  f32x4 lacc = (f32x4){0.f, 0.f, 0.f, 0.f};
#pragma unroll
  for (int dg = 0; dg < 4; ++dg) oacc[dg] = (f32x4){0.f, 0.f, 0.f, 0.f};
  float mrun = -INFINITY;

  const short8 ONES = {0x3F80, 0x3F80, 0x3F80, 0x3F80,
                       0x3F80, 0x3F80, 0x3F80, 0x3F80};  // bf16 1.0 x8

  // stage one 64-key tile (K 8KB + V 8KB) into buffer nb; 1 GLL each per thread
  auto stage = [&](int nb, int kt) {
    const int grow = wave * 8 + srow;               // 0..63
    GLL16(Kp + (size_t)(kt + grow) * 1024 + feK, &sK[nb][wave * 8][0]);
    GLL16(Vp + (size_t)grow * 2048 + kt + feV,   &sV[nb][wave * 8][0]);
  };

  // process one 32-key subtile from buffer nb
  auto proc_sub = [&](int nb, int sub) {
    short8 kf[2][2];
#pragma unroll
    for (int t = 0; t < 2; ++t) {
      const int r = sub * 32 + keyperm + 4 * t;
#pragma unroll
      for (int hf = 0; hf < 2; ++hf)
        kf[t][hf] = *(const short8*)&sK[nb][r][(hf * 32 + g * 8) ^ swzK8];
    }
    short8 vf[4];
#pragma unroll
    for (int dg = 0; dg < 4; ++dg)
      vf[dg] = *(const short8*)&sV[nb][dg * 16 + rl][(sub * 32 + g * 8) ^ swzV8];

    f32x4 sc[2];
    __builtin_amdgcn_s_setprio(1);
#pragma unroll
    for (int t = 0; t < 2; ++t) {
      f32x4 a = (f32x4){0.f, 0.f, 0.f, 0.f};
      a = mfma_bf16(kf[t][0], qf[0], a);
      a = mfma_bf16(kf[t][1], qf[1], a);
      sc[t] = a;
    }
    __builtin_amdgcn_s_setprio(0);

    float p2[8];
#pragma unroll
    for (int t = 0; t < 2; ++t)
#pragma unroll
      for (int r = 0; r < 4; ++r) p2[t * 4 + r] = sc[t][r];
    float a0 = fmaxf(fmaxf(p2[0], p2[1]), p2[2]);
    float a1 = fmaxf(fmaxf(p2[3], p2[4]), p2[5]);
    float a2 = fmaxf(p2[6], p2[7]);
    float tm = fmaxf(fmaxf(a0, a1), a2);
    // defer-max: rescale only when tile max grows past THR=8 (exp2 domain)
    if (!__all(tm <= mrun + 8.0f)) {
      tm = fmaxf(tm, __shfl_xor(tm, 16));
      tm = fmaxf(tm, __shfl_xor(tm, 32));
      float mnew = fmaxf(mrun, tm);
      float sfac = __builtin_amdgcn_exp2f(mrun - mnew);
      mrun = mnew;
#pragma unroll
      for (int dg = 0; dg < 4; ++dg)
#pragma unroll
        for (int r = 0; r < 4; ++r) oacc[dg][r] *= sfac;
      lacc[0] *= sfac;   // only reg 0 is ever read
    }
    short8 pb;
#pragma unroll
    for (int j2 = 0; j2 < 8; ++j2)
      pb[j2] = (short)f2bf(__builtin_amdgcn_exp2f(p2[j2] - mrun));

    __builtin_amdgcn_s_setprio(1);
    lacc = mfma_bf16(ONES, pb, lacc);   // row-sum on matrix pipe
#pragma unroll
    for (int dg = 0; dg < 4; ++dg)
      oacc[dg] = mfma_bf16(vf[dg], pb, oacc[dg]);
    __builtin_amdgcn_s_setprio(0);
  };

  // double-buffered main loop: 32 tiles of 64 keys, unrolled x2 (static nb)
  stage(0, 0);
  __syncthreads();
  for (int kt = 0; kt < 2048; kt += 128) {
    stage(1, kt + 64);
    proc_sub(0, 0);
    proc_sub(0, 1);
    __syncthreads();                     // buf1 staged; buf0 fully read
    if (kt + 128 < 2048) stage(0, kt + 128);
    proc_sub(1, 0);
    proc_sub(1, 1);
    __syncthreads();
  }

  float inv = 1.0f / lacc[0];
  int qrow = qbase + rl;
  u16* op = O + (size_t)(b * 2048 + qrow) * 1024 + h * 64;
#pragma unroll
  for (int dg = 0; dg < 4; ++dg) {
    u16x4 pk;
#pragma unroll
    for (int r = 0; r < 4; ++r) pk[r] = f2bf(oacc[dg][r] * inv);
    *(u16x4*)&op[dg * 16 + g * 4] = pk;
  }
}

// ---------------------------------------------------------------- launch
extern "C" void kernel_launch(void* const* d_in, const int* in_sizes, int n_in,
                              void* d_out, int out_size, void* d_ws, size_t ws_size,
                              hipStream_t stream) {
  const float* x  = (const float*)d_in[0];
  const float* Wq = (const float*)d_in[1];
  const float* bq = (const float*)d_in[2];
  const float* Wk = (const float*)d_in[3];
  const float* bk = (const float*)d_in[4];
  const float* Wv = (const float*)d_in[5];
  const float* bv = (const float*)d_in[6];
  const float* Wo = (const float*)d_in[7];
  const float* bo = (const float*)d_in[8];

  char* ws = (char*)d_ws;
  const size_t MB = 1024 * 1024;
  u16* Xb  = (u16*)(ws + 0 * MB);
  u16* Wqb = (u16*)(ws + 8 * MB);
  u16* Wkb = (u16*)(ws + 10 * MB);
  u16* Wvb = (u16*)(ws + 12 * MB);
  u16* Wob = (u16*)(ws + 14 * MB);
  u16* Qb  = (u16*)(ws + 16 * MB);
  u16* Kb  = (u16*)(ws + 24 * MB);
  u16* Vtb = (u16*)(ws + 32 * MB);
  u16* Ob  = (u16*)(ws + 40 * MB);

  cast_all<<<dim3(4096, 1, 5), 256, 0, stream>>>(x, Wq, Wk, Wv, Wo,
                                                 Xb, Wqb, Wkb, Wvb, Wob);
  gemm_qkv<<<dim3(8, 32, 3), 256, 0, stream>>>(Xb, Wqb, Wkb, Wvb,
                                               bq, bk, bv, Qb, Kb, Vtb);
  attn_fwd<<<dim3(512), 512, 0, stream>>>(Qb, Kb, Vtb, Ob);
  gemm_out<<<dim3(8, 32), 256, 0, stream>>>(Ob, Wob, bo, (float*)d_out);
}

// Round 7
// 116.088 us; speedup vs baseline: 2.5815x; 1.0079x over previous
//
#include <hip/hip_runtime.h>
#include <hip/hip_bf16.h>

// MultiHeadAttention fused pipeline, round 7: split-KV attention (LDS-traffic fix).
// B=2 S=2048 D=1024 H=16 dk=64.
// ws layout (48 MB): Xb 8M | Wq/Wk/Wv/Wo bf16 2M each | Qb 8M | Kb 8M | Vt 8M | Ob 8M
// Changes vs R6:
//  - attn is LDS-BW-bound (R6: 2.4GB LDS traffic ~= measured 48us). Fix: back to
//    32 q-rows/wave (halves per-key LDS re-reads), keep 8-wave/512-thr blocks by
//    SPLIT-KV: wave w = (qslot w>>1, half w&1); half h covers keys [1024h,1024h+1024).
//    LDS read traffic 2.1GB -> 1.07GB. Epilogue: online-softmax merge of the two
//    halves via a 36KB LDS buffer. Grid 512 (XCD-resident K/V preserved).

typedef unsigned short u16;
typedef __attribute__((ext_vector_type(4))) unsigned short u16x4;
typedef __attribute__((ext_vector_type(8))) short short8;   // 8 x bf16 (4 VGPRs)
typedef __attribute__((ext_vector_type(4))) float f32x4;

__device__ __forceinline__ u16 f2bf(float f) {  // native RNE f32->bf16
  __bf16 b = (__bf16)f;
  return __builtin_bit_cast(unsigned short, b);
}

__device__ __forceinline__ f32x4 mfma_bf16(short8 a, short8 b, f32x4 c) {
  return __builtin_amdgcn_mfma_f32_16x16x32_bf16(a, b, c, 0, 0, 0);
}

#define GLL16(gp, lp) __builtin_amdgcn_global_load_lds( \
    (const __attribute__((address_space(1))) void*)(gp), \
    (__attribute__((address_space(3))) void*)(lp), 16, 0, 0)

#define QSCALE 0.18033688011112042f   /* 0.125 * log2(e) */

// ---------------------------------------------------------------- casts
__global__ __launch_bounds__(256) void cast_all(
    const float* __restrict__ x,
    const float* __restrict__ wq, const float* __restrict__ wk,
    const float* __restrict__ wv, const float* __restrict__ wo,
    u16* __restrict__ xb, u16* __restrict__ wqb, u16* __restrict__ wkb,
    u16* __restrict__ wvb, u16* __restrict__ wob)
{
  const int z = blockIdx.z;
  const float* s; u16* d; int n4;
  if (z == 0)      { s = x;  d = xb;  n4 = 1048576; }
  else if (z == 1) { s = wq; d = wqb; n4 = 262144; }
  else if (z == 2) { s = wk; d = wkb; n4 = 262144; }
  else if (z == 3) { s = wv; d = wvb; n4 = 262144; }
  else             { s = wo; d = wob; n4 = 262144; }
  int i = blockIdx.x * 256 + threadIdx.x;
  if (i >= n4) return;
  float4 v = ((const float4*)s)[i];
  u16x4 o; o[0] = f2bf(v.x); o[1] = f2bf(v.y); o[2] = f2bf(v.z); o[3] = f2bf(v.w);
  ((u16x4*)d)[i] = o;
}

// -------------------------------------------------- 128x128 GEMM core, C = A * B^T
__device__ __forceinline__ void gemm_core(const u16* __restrict__ A,
                                          const u16* __restrict__ B,
                                          u16* sA, u16* sB, f32x4 acc[4][4])
{
  const int tid = threadIdx.x;
  const int lane = tid & 63, wave = tid >> 6;
  const int wr = wave >> 1, wc = wave & 1;
  const int m0 = blockIdx.y * 128, n0 = blockIdx.x * 128;
  const u16* ga = A + (size_t)(m0 + (tid >> 2)) * 1024 + (tid & 3) * 8;
  const u16* gb = B + (size_t)(n0 + (tid >> 2)) * 1024 + (tid & 3) * 8;
  u16* la0 = sA + wave * 512;          u16* la1 = sA + 2048 + wave * 512;
  u16* lb0 = sB + wave * 512;          u16* lb1 = sB + 2048 + wave * 512;
  const int rl = lane & 15, kg = (lane >> 4) * 8;

  for (int k0 = 0; k0 < 1024; k0 += 32) {
    GLL16(ga + k0,             la0);
    GLL16(ga + 64 * 1024 + k0, la1);
    GLL16(gb + k0,             lb0);
    GLL16(gb + 64 * 1024 + k0, lb1);
    __syncthreads();
    short8 af[4], bf_[4];
#pragma unroll
    for (int m = 0; m < 4; ++m) af[m]  = *(const short8*)&sA[(wr * 64 + m * 16 + rl) * 32 + kg];
#pragma unroll
    for (int n = 0; n < 4; ++n) bf_[n] = *(const short8*)&sB[(wc * 64 + n * 16 + rl) * 32 + kg];
#pragma unroll
    for (int m = 0; m < 4; ++m)
#pragma unroll
      for (int n = 0; n < 4; ++n)
        acc[m][n] = mfma_bf16(af[m], bf_[n], acc[m][n]);
    __syncthreads();
  }
}

// QKV projections fused via blockIdx.z. z=0 -> Q (PRE-SCALED by QSCALE),
// z=1 -> K, z=2 -> V written TRANSPOSED: Vt[(b*1024+hd)][s].
__global__ __launch_bounds__(256) void gemm_qkv(
    const u16* __restrict__ X,
    const u16* __restrict__ Wqb, const u16* __restrict__ Wkb, const u16* __restrict__ Wvb,
    const float* __restrict__ bq, const float* __restrict__ bk, const float* __restrict__ bv,
    u16* __restrict__ Qo, u16* __restrict__ Ko, u16* __restrict__ Vt)
{
  __shared__ u16 sA[4096], sB[4096];
  const int z = blockIdx.z;
  const u16* W = (z == 0) ? Wqb : (z == 1) ? Wkb : Wvb;
  const float* bias = (z == 0) ? bq : (z == 1) ? bk : bv;

  f32x4 acc[4][4];
#pragma unroll
  for (int m = 0; m < 4; ++m)
#pragma unroll
    for (int n = 0; n < 4; ++n) acc[m][n] = (f32x4){0.f, 0.f, 0.f, 0.f};

  gemm_core(X, W, sA, sB, acc);

  const int lane = threadIdx.x & 63, wave = threadIdx.x >> 6;
  const int wr = wave >> 1, wc = wave & 1;
  const int m0 = blockIdx.y * 128, n0 = blockIdx.x * 128;
  const int rl = lane & 15, rg = (lane >> 4) * 4;

  if (z < 2) {
    u16* dst = (z == 0) ? Qo : Ko;
    const float cs = (z == 0) ? QSCALE : 1.0f;
#pragma unroll
    for (int n = 0; n < 4; ++n) {
      int col = n0 + wc * 64 + n * 16 + rl;
      float bb = bias[col];
#pragma unroll
      for (int m = 0; m < 4; ++m) {
        int row0 = m0 + wr * 64 + m * 16 + rg;
#pragma unroll
        for (int r = 0; r < 4; ++r)
          dst[(size_t)(row0 + r) * 1024 + col] = f2bf((acc[m][n][r] + bb) * cs);
      }
    }
  } else {
#pragma unroll
    for (int n = 0; n < 4; ++n) {
      int col = n0 + wc * 64 + n * 16 + rl;   // hd = h*64+d
      float bb = bias[col];
#pragma unroll
      for (int m = 0; m < 4; ++m) {
        int row0 = m0 + wr * 64 + m * 16 + rg;          // b*2048 + s
        int bidx = row0 >> 11, sl = row0 & 2047;
        u16x4 pk;
#pragma unroll
        for (int r = 0; r < 4; ++r) pk[r] = f2bf(acc[m][n][r] + bb);
        *(u16x4*)&Vt[((size_t)(bidx * 1024 + col)) * 2048 + sl] = pk;
      }
    }
  }
}

// Output projection: out(fp32) = Ob @ Wo^T + bo
__global__ __launch_bounds__(256) void gemm_out(
    const u16* __restrict__ Ob, const u16* __restrict__ Wob,
    const float* __restrict__ bo, float* __restrict__ Out)
{
  __shared__ u16 sA[4096], sB[4096];
  f32x4 acc[4][4];
#pragma unroll
  for (int m = 0; m < 4; ++m)
#pragma unroll
    for (int n = 0; n < 4; ++n) acc[m][n] = (f32x4){0.f, 0.f, 0.f, 0.f};

  gemm_core(Ob, Wob, sA, sB, acc);

  const int lane = threadIdx.x & 63, wave = threadIdx.x >> 6;
  const int wr = wave >> 1, wc = wave & 1;
  const int m0 = blockIdx.y * 128, n0 = blockIdx.x * 128;
  const int rl = lane & 15, rg = (lane >> 4) * 4;
#pragma unroll
  for (int n = 0; n < 4; ++n) {
    int col = n0 + wc * 64 + n * 16 + rl;
    float bb = bo[col];
#pragma unroll
    for (int m = 0; m < 4; ++m) {
      int row0 = m0 + wr * 64 + m * 16 + rg;
#pragma unroll
      for (int r = 0; r < 4; ++r)
        Out[(size_t)(row0 + r) * 1024 + col] = acc[m][n][r] + bb;
    }
  }
}

// ---------------------------------------------------------------- flash attention
// Split-KV: block = 512 thr = 8 waves = 4 q-slots (32 q-rows) x 2 K-halves.
// Wave (qslot=w>>1, half=w&1): keys [half*1024, half*1024+1024) in 32-key tiles.
// LDS: sK rows = half*32+local key (swizzled as R6); sV cols = 8-group involution
// over both halves. Staged once per block per tile-pair via global_load_lds.
// Epilogue: half-1 waves publish (oacc,m,l) to mbuf; half-0 waves merge + store.
// Grid 512: XCD x owns bh {4x..4x+3} (2MB K/V in its L2).
__global__ __launch_bounds__(512, 4) void attn_fwd(
    const u16* __restrict__ Q, const u16* __restrict__ K,
    const u16* __restrict__ Vt, u16* __restrict__ O)
{
  __shared__ u16 sK[2][64][64];   // [buf][half*32+key][d], elem-swizzled
  __shared__ u16 sV[2][64][64];   // [buf][d][keygrp-involution cols]
  __shared__ float mbuf[9216];    // 4 qslots x 64 lanes x 36 floats (merge)

  const int tid = threadIdx.x, lane = tid & 63, wave = tid >> 6;  // wave 0..7
  const int rl = lane & 15, g = lane >> 4;
  const int qslot = wave >> 1, half = wave & 1;

  const int bflat = blockIdx.x;
  const int xcd = bflat & 7, j = bflat >> 3;        // 512 = 8 XCD * 64
  const int bh = xcd * 4 + (j >> 4);                // 4 bh per XCD (2MB in L2)
  const int qidx = j & 15;
  const int b = bh >> 4, h = bh & 15;
  const int qbase = qidx * 128 + qslot * 32;

  const u16* Qp = Q + (size_t)(b * 2048 + qbase) * 1024 + h * 64;
  const u16* Kp = K + (size_t)(b * 2048) * 1024 + h * 64;
  const u16* Vp = Vt + (size_t)(bh * 64) * 2048;

  short8 qf[2][2];
#pragma unroll
  for (int qg = 0; qg < 2; ++qg)
#pragma unroll
    for (int hf = 0; hf < 2; ++hf)
      qf[qg][hf] = *(const short8*)&Qp[(size_t)(qg * 16 + rl) * 1024 + hf * 32 + g * 8];

  const int keyperm = 8 * (rl >> 2) + (rl & 3);
  const int swzK8 = (((rl & 3) | (((rl >> 2) & 1) << 2))) * 8;

  // staging constants (thread-fixed)
  const int krow = tid >> 3;                        // 0..63
  const int feK = (((tid & 7) ^ (krow & 3)) * 8) ^ ((wave & 1) * 32);
  const int gp  = (tid & 7) ^ (krow & 7);           // V key-group involution

  f32x4 oacc[2][4];
  f32x4 lacc[2];
#pragma unroll
  for (int qg = 0; qg < 2; ++qg) {
    lacc[qg] = (f32x4){0.f, 0.f, 0.f, 0.f};
#pragma unroll
    for (int dg = 0; dg < 4; ++dg) oacc[qg][dg] = (f32x4){0.f, 0.f, 0.f, 0.f};
  }
  float mrun[2] = {-INFINITY, -INFINITY};

  const short8 ONES = {0x3F80, 0x3F80, 0x3F80, 0x3F80,
                       0x3F80, 0x3F80, 0x3F80, 0x3F80};  // bf16 1.0 x8

  // stage tile t (32 keys per half, both halves): 1 K-GLL + 1 V-GLL per thread
  auto stage = [&](int nb, int t) {
    GLL16(Kp + (size_t)(((krow >> 5) << 10) + t * 32 + (krow & 31)) * 1024 + feK,
          &sK[nb][wave * 8][0]);
    GLL16(Vp + (size_t)krow * 2048 + ((gp >> 2) << 10) + t * 32 + (gp & 3) * 8,
          &sV[nb][wave * 8][0]);
  };

  // process this wave's 32-key tile from buffer nb
  auto proc = [&](int nb) {
    short8 kf[2][2];
#pragma unroll
    for (int t2 = 0; t2 < 2; ++t2) {
      const int r = half * 32 + keyperm + 4 * t2;
#pragma unroll
      for (int hf = 0; hf < 2; ++hf)
        kf[t2][hf] = *(const short8*)&sK[nb][r][(hf * 32 + g * 8) ^ swzK8];
    }
    short8 vf[4];
#pragma unroll
    for (int dg = 0; dg < 4; ++dg)
      vf[dg] = *(const short8*)&sV[nb][dg * 16 + rl][(((half << 2) | g) ^ (rl & 7)) * 8];

    f32x4 sc[2][2];
    __builtin_amdgcn_s_setprio(1);
#pragma unroll
    for (int qg = 0; qg < 2; ++qg)
#pragma unroll
      for (int t2 = 0; t2 < 2; ++t2) {
        f32x4 a = (f32x4){0.f, 0.f, 0.f, 0.f};
        a = mfma_bf16(kf[t2][0], qf[qg][0], a);
        a = mfma_bf16(kf[t2][1], qf[qg][1], a);
        sc[qg][t2] = a;
      }
    __builtin_amdgcn_s_setprio(0);

    short8 pb[2];
#pragma unroll
    for (int qg = 0; qg < 2; ++qg) {
      float p2[8];
#pragma unroll
      for (int t2 = 0; t2 < 2; ++t2)
#pragma unroll
        for (int r = 0; r < 4; ++r) p2[t2 * 4 + r] = sc[qg][t2][r];
      float a0 = fmaxf(fmaxf(p2[0], p2[1]), p2[2]);
      float a1 = fmaxf(fmaxf(p2[3], p2[4]), p2[5]);
      float a2 = fmaxf(p2[6], p2[7]);
      float tm = fmaxf(fmaxf(a0, a1), a2);
      // defer-max: rescale only when tile max grows past THR=8 (exp2 domain)
      if (!__all(tm <= mrun[qg] + 8.0f)) {
        tm = fmaxf(tm, __shfl_xor(tm, 16));
        tm = fmaxf(tm, __shfl_xor(tm, 32));
        float mnew = fmaxf(mrun[qg], tm);
        float sfac = __builtin_amdgcn_exp2f(mrun[qg] - mnew);
        mrun[qg] = mnew;
#pragma unroll
        for (int dg = 0; dg < 4; ++dg)
#pragma unroll
          for (int r = 0; r < 4; ++r) oacc[qg][dg][r] *= sfac;
        lacc[qg][0] *= sfac;   // only reg 0 is ever read
      }
      short8 pk;
#pragma unroll
      for (int j2 = 0; j2 < 8; ++j2)
        pk[j2] = (short)f2bf(__builtin_amdgcn_exp2f(p2[j2] - mrun[qg]));
      pb[qg] = pk;
      lacc[qg] = mfma_bf16(ONES, pb[qg], lacc[qg]);   // row-sum on matrix pipe
    }
    __builtin_amdgcn_s_setprio(1);
#pragma unroll
    for (int dg = 0; dg < 4; ++dg)
#pragma unroll
      for (int qg = 0; qg < 2; ++qg)
        oacc[qg][dg] = mfma_bf16(vf[dg], pb[qg], oacc[qg][dg]);
    __builtin_amdgcn_s_setprio(0);
  };

  // double-buffered loop: 32 tiles of 32 keys per half (both halves in parallel)
  stage(0, 0);
  __syncthreads();
  for (int t = 0; t < 32; t += 2) {
    stage(1, t + 1);
    proc(0);
    __syncthreads();
    if (t + 2 < 32) stage(0, t + 2);
    proc(1);
    __syncthreads();
  }

  // merge the two K-halves (online-softmax combine), half1 -> mbuf -> half0
  const int mb = (qslot * 64 + lane) * 36;
  if (half == 1) {
#pragma unroll
    for (int qg = 0; qg < 2; ++qg) {
#pragma unroll
      for (int dg = 0; dg < 4; ++dg)
#pragma unroll
        for (int r = 0; r < 4; ++r)
          mbuf[mb + qg * 18 + dg * 4 + r] = oacc[qg][dg][r];
      mbuf[mb + qg * 18 + 16] = mrun[qg];
      mbuf[mb + qg * 18 + 17] = lacc[qg][0];
    }
  }
  __syncthreads();
  if (half == 0) {
#pragma unroll
    for (int qg = 0; qg < 2; ++qg) {
      float m2 = mbuf[mb + qg * 18 + 16];
      float l2 = mbuf[mb + qg * 18 + 17];
      float mnew = fmaxf(mrun[qg], m2);
      float fa = __builtin_amdgcn_exp2f(mrun[qg] - mnew);
      float fb = __builtin_amdgcn_exp2f(m2 - mnew);
      float inv = 1.0f / (lacc[qg][0] * fa + l2 * fb);
      int qrow = qbase + qg * 16 + rl;
      u16* op = O + (size_t)(b * 2048 + qrow) * 1024 + h * 64;
#pragma unroll
      for (int dg = 0; dg < 4; ++dg) {
        u16x4 pk;
#pragma unroll
        for (int r = 0; r < 4; ++r)
          pk[r] = f2bf((oacc[qg][dg][r] * fa + mbuf[mb + qg * 18 + dg * 4 + r] * fb) * inv);
        *(u16x4*)&op[dg * 16 + g * 4] = pk;
      }
    }
  }
}

// ---------------------------------------------------------------- launch
extern "C" void kernel_launch(void* const* d_in, const int* in_sizes, int n_in,
                              void* d_out, int out_size, void* d_ws, size_t ws_size,
                              hipStream_t stream) {
  const float* x  = (const float*)d_in[0];
  const float* Wq = (const float*)d_in[1];
  const float* bq = (const float*)d_in[2];
  const float* Wk = (const float*)d_in[3];
  const float* bk = (const float*)d_in[4];
  const float* Wv = (const float*)d_in[5];
  const float* bv = (const float*)d_in[6];
  const float* Wo = (const float*)d_in[7];
  const float* bo = (const float*)d_in[8];

  char* ws = (char*)d_ws;
  const size_t MB = 1024 * 1024;
  u16* Xb  = (u16*)(ws + 0 * MB);
  u16* Wqb = (u16*)(ws + 8 * MB);
  u16* Wkb = (u16*)(ws + 10 * MB);
  u16* Wvb = (u16*)(ws + 12 * MB);
  u16* Wob = (u16*)(ws + 14 * MB);
  u16* Qb  = (u16*)(ws + 16 * MB);
  u16* Kb  = (u16*)(ws + 24 * MB);
  u16* Vtb = (u16*)(ws + 32 * MB);
  u16* Ob  = (u16*)(ws + 40 * MB);

  cast_all<<<dim3(4096, 1, 5), 256, 0, stream>>>(x, Wq, Wk, Wv, Wo,
                                                 Xb, Wqb, Wkb, Wvb, Wob);
  gemm_qkv<<<dim3(8, 32, 3), 256, 0, stream>>>(Xb, Wqb, Wkb, Wvb,
                                               bq, bk, bv, Qb, Kb, Vtb);
  attn_fwd<<<dim3(512), 512, 0, stream>>>(Qb, Kb, Vtb, Ob);
  gemm_out<<<dim3(8, 32), 256, 0, stream>>>(Ob, Wob, bo, (float*)d_out);
}